// Round 2
// baseline (211.353 us; speedup 1.0000x reference)
//
#include <hip/hip_runtime.h>
#include <math.h>

#define GSZ 512          // oversampled grid size (both dims)
#define NSZ 256          // image size
#define NBATCH 8
#define MPTS 131072      // points per batch (2^17)
#define PI_F 3.14159265358979f

// BETA = pi * sqrt((6/2)^2 * (2-0.5)^2 - 0.8) = pi*sqrt(19.45)
#define BETA_F 13.8551004f
#define BETA2_F (BETA_F * BETA_F)

// ---------------------------------------------------------------- helpers

// de-apodization coefficient for index i in [0,256): sqrt(t)/sinh(sqrt(t))
__device__ __forceinline__ float apod(int i) {
    float x = (float)(i - 128);
    float arg = PI_F * 6.0f * x * (1.0f / 512.0f);
    float t = BETA2_F - arg * arg;
    float st = sqrtf(t);
    return st / sinhf(st);
}

// modified Bessel I0, Abramowitz & Stegun 9.8.1/9.8.2 (~2e-7 rel err)
__device__ __forceinline__ float bessi0(float x) {
    float ax = fabsf(x);
    if (ax < 3.75f) {
        float y = ax * (1.0f / 3.75f);
        y *= y;
        return 1.0f + y * (3.5156229f + y * (3.0899424f + y * (1.2067492f
             + y * (0.2659732f + y * (0.0360768f + y * 0.0045813f)))));
    } else {
        float y = 3.75f / ax;
        float p = 0.39894228f + y * (0.01328592f + y * (0.00225319f + y * (-0.00157565f
             + y * (0.00916281f + y * (-0.02057706f + y * (0.02635537f + y * (-0.01647633f
             + y * 0.00392377f)))))));
        return p * __expf(ax) * rsqrtf(ax);
    }
}

// 512-point forward FFT (Stockham radix-2, DIF), 256 threads, ping-pong LDS.
// Returns pointer to the buffer holding the result (naturally ordered).
__device__ __forceinline__ float2* fft512(float2* bufA, float2* bufB, int t) {
    float2* src = bufA;
    float2* dst = bufB;
    int l = 256;
    #pragma unroll
    for (int s = 0; s < 9; ++s) {
        __syncthreads();
        int m = 1 << s;
        int j = t >> s;
        int k = t & (m - 1);
        float2 a = src[t];
        float2 b = src[t + 256];
        float ang = -PI_F * (float)j / (float)l;   // l is unroll-constant
        float sn, c;
        __sincosf(ang, &sn, &c);                   // NOTE: sin FIRST, cos second
        float dx = a.x - b.x, dy = a.y - b.y;
        int base = k + (j << (s + 1));             // k + 2*j*m
        dst[base]     = make_float2(a.x + b.x, a.y + b.y);
        dst[base + m] = make_float2(dx * c - dy * sn, dx * sn + dy * c);
        float2* tmp = src; src = dst; dst = tmp;
        l >>= 1;
    }
    __syncthreads();
    return src;
}

// ---------------------------------------------------------------- pass 1
// One block per (b, y). Builds the apodized/ifftshifted row (256 nonzero of
// 512) and FFTs along x. Rows in the zero band just store zeros (ws is
// poisoned, must write everything pass2 reads).
__global__ __launch_bounds__(256) void pass1_rowfft(const float* __restrict__ image,
                                                    float2* __restrict__ T) {
    __shared__ float2 bufA[512];
    __shared__ float2 bufB[512];
    int t = threadIdx.x;
    int wg = blockIdx.x;           // b*512 + y
    int y = wg & 511;
    int b = wg >> 9;
    float2* Trow = T + ((size_t)wg << 9);

    bool rowValid = (y < 128) || (y >= 384);
    if (!rowValid) {
        float2 z = make_float2(0.f, 0.f);
        Trow[t] = z;
        Trow[t + 256] = z;
        return;
    }
    int iy = (y < 128) ? (y + 128) : (y - 384);
    float ay = apod(iy);
    const float* irow = image + ((size_t)b * NSZ + iy) * NSZ;

    // shifted[y, x]: x=t nonzero iff t<128 (ix=t+128); x=t+256 nonzero iff
    // t>=128 (ix=t-128). Each thread supplies exactly one nonzero value.
    float v0 = 0.f, v1 = 0.f;
    if (t < 128) {
        int ix = t + 128;
        v0 = irow[ix] * ay * apod(ix);
    } else {
        int ix = t - 128;
        v1 = irow[ix] * ay * apod(ix);
    }
    bufA[t]       = make_float2(v0, 0.f);
    bufA[t + 256] = make_float2(v1, 0.f);

    float2* res = fft512(bufA, bufB, t);
    Trow[t]       = res[t];
    Trow[t + 256] = res[t + 256];
}

// ---------------------------------------------------------------- pass 2
// One block per (b, k2). FFT along y (column access, strided).
__global__ __launch_bounds__(256) void pass2_colfft(const float2* __restrict__ T,
                                                    float2* __restrict__ kgrid) {
    __shared__ float2 bufA[512];
    __shared__ float2 bufB[512];
    int t = threadIdx.x;
    int wg = blockIdx.x;           // b*512 + k2
    int k2 = wg & 511;
    int b = wg >> 9;
    const float2* Tb = T + ((size_t)b << 18);
    bufA[t]       = Tb[((size_t)t << 9) + k2];
    bufA[t + 256] = Tb[((size_t)(t + 256) << 9) + k2];

    float2* res = fft512(bufA, bufB, t);

    float2* Kb = kgrid + ((size_t)b << 18);
    Kb[((size_t)t << 9) + k2]         = res[t];
    Kb[((size_t)(t + 256) << 9) + k2] = res[t + 256];
}

// ---------------------------------------------------------------- pass 3
// One thread per (b, m): 6x6 Kaiser-Bessel gather, * dcf, write (2,B,M).
__global__ __launch_bounds__(256) void interp_kb(const float* __restrict__ ktraj,
                                                 const float* __restrict__ dcf,
                                                 const float2* __restrict__ kgrid,
                                                 float* __restrict__ out) {
    int gid = blockIdx.x * 256 + threadIdx.x;   // b*M + m
    int b = gid >> 17;                          // M = 2^17
    int m = gid & (MPTS - 1);

    const float SCALE = (float)GSZ / (2.0f * PI_F);
    float tm1 = ktraj[((size_t)b * 2) * MPTS + m] * SCALE;
    float tm2 = ktraj[((size_t)b * 2 + 1) * MPTS + m] * SCALE;
    float f1 = floorf(tm1), f2 = floorf(tm2);

    float w1[6], w2[6];
    int i1[6], i2[6];
    #pragma unroll
    for (int j = 0; j < 6; ++j) {
        float off = (float)(j - 2);             // offs = [-2..3]
        float u1 = tm1 - (f1 + off);
        float u2 = tm2 - (f2 + off);
        float x1 = u1 * (1.0f / 3.0f);          // 2u/J, J=6
        float x2 = u2 * (1.0f / 3.0f);
        float t1 = 1.0f - x1 * x1;
        float t2 = 1.0f - x2 * x2;
        w1[j] = (t1 > 0.f) ? bessi0(BETA_F * sqrtf(t1)) : 0.f;
        w2[j] = (t2 > 0.f) ? bessi0(BETA_F * sqrtf(t2)) : 0.f;
        i1[j] = ((int)(f1 + off)) & 511;        // mod 512 (pow2, handles negatives)
        i2[j] = ((int)(f2 + off)) & 511;
    }

    const float2* Kb = kgrid + ((size_t)b << 18);
    float re = 0.f, im = 0.f;
    #pragma unroll
    for (int a = 0; a < 6; ++a) {
        const float2* Krow = Kb + ((size_t)i1[a] << 9);
        float rr = 0.f, ii = 0.f;
        #pragma unroll
        for (int c = 0; c < 6; ++c) {
            float2 v = Krow[i2[c]];
            rr += v.x * w2[c];
            ii += v.y * w2[c];
        }
        re += w1[a] * rr;
        im += w1[a] * ii;
    }
    float d = dcf[gid];
    out[gid] = re * d;                          // real plane (0,b,m)
    out[gid + NBATCH * MPTS] = im * d;          // imag plane (1,b,m)
}

// ---------------------------------------------------------------- launch

extern "C" void kernel_launch(void* const* d_in, const int* in_sizes, int n_in,
                              void* d_out, int out_size, void* d_ws, size_t ws_size,
                              hipStream_t stream) {
    const float* image = (const float*)d_in[0];   // (8,256,256) f32
    const float* ktraj = (const float*)d_in[1];   // (8,2,131072) f32
    const float* dcf   = (const float*)d_in[2];   // (8,131072) f32
    float* out = (float*)d_out;                   // (2,8,131072) f32

    // workspace: T (row-FFT intermediate) + kgrid, each B*512*512 complex64
    float2* T     = (float2*)d_ws;
    float2* kgrid = T + (size_t)NBATCH * GSZ * GSZ;   // +16.78 MB

    pass1_rowfft<<<NBATCH * GSZ, 256, 0, stream>>>(image, T);
    pass2_colfft<<<NBATCH * GSZ, 256, 0, stream>>>(T, kgrid);
    interp_kb<<<(NBATCH * MPTS) / 256, 256, 0, stream>>>(ktraj, dcf, kgrid, out);
}

// Round 3
// 168.387 us; speedup vs baseline: 1.2552x; 1.2552x over previous
//
#include <hip/hip_runtime.h>
#include <math.h>

#define GSZ 512
#define NSZ 256
#define NBATCH 8
#define MPTS 131072
#define PI_F 3.14159265358979f
#define BETA_F 13.8551004f
#define BETA2_F (BETA_F * BETA_F)
#define RSQ2 0.70710678f
// LDS pad: +1 float2 every 8 → stage-0/1 strided writes drop 32-way→4-way
#define PADIDX(i) ((i) + ((i) >> 3))
// padded row buffer: PADIDX(511)=574; stride 578 destaggers the 4 sub-buffers

// ---------------------------------------------------------------- helpers

__device__ __forceinline__ float apod(int i) {
    float x = (float)(i - 128);
    float arg = PI_F * 6.0f * x * (1.0f / 512.0f);
    float t = BETA2_F - arg * arg;
    float st = sqrtf(t);
    return st / sinhf(st);
}

__device__ __forceinline__ float bessi0(float x) {
    float ax = fabsf(x);
    if (ax < 3.75f) {
        float y = ax * (1.0f / 3.75f);
        y *= y;
        return 1.0f + y * (3.5156229f + y * (3.0899424f + y * (1.2067492f
             + y * (0.2659732f + y * (0.0360768f + y * 0.0045813f)))));
    } else {
        float y = 3.75f / ax;
        float p = 0.39894228f + y * (0.01328592f + y * (0.00225319f + y * (-0.00157565f
             + y * (0.00916281f + y * (-0.02057706f + y * (0.02635537f + y * (-0.01647633f
             + y * 0.00392377f)))))));
        return p * __expf(ax) * rsqrtf(ax);
    }
}

__device__ __forceinline__ float2 cadd(float2 a, float2 b){ return make_float2(a.x+b.x, a.y+b.y); }
__device__ __forceinline__ float2 csub(float2 a, float2 b){ return make_float2(a.x-b.x, a.y-b.y); }
__device__ __forceinline__ float2 cmul(float2 a, float2 b){ return make_float2(a.x*b.x-a.y*b.y, a.x*b.y+a.y*b.x); }
__device__ __forceinline__ float2 mul_negi(float2 a){ return make_float2(a.y, -a.x); }   // *(-i)
__device__ __forceinline__ float2 mul_posi(float2 a){ return make_float2(-a.y, a.x); }   // *(+i)
__device__ __forceinline__ float2 mul_w81(float2 a){ return make_float2(RSQ2*(a.x+a.y), RSQ2*(a.y-a.x)); } // *e^{-iπ/4}
__device__ __forceinline__ float2 mul_w83(float2 a){ return make_float2(RSQ2*(a.y-a.x), -RSQ2*(a.x+a.y)); } // *e^{-3iπ/4}

// combine E[0..3], O[0..3] (DFT4 halves) into DFT8 outputs y[0..7]
__device__ __forceinline__ void dft8_combine(float2 E0, float2 E1, float2 E2, float2 E3,
                                             float2 O0, float2 O1, float2 O2, float2 O3,
                                             float2* y) {
    float2 c1 = mul_w81(O1), c2 = mul_negi(O2), c3 = mul_w83(O3);
    y[0] = cadd(E0, O0); y[4] = csub(E0, O0);
    y[1] = cadd(E1, c1); y[5] = csub(E1, c1);
    y[2] = cadd(E2, c2); y[6] = csub(E2, c2);
    y[3] = cadd(E3, c3); y[7] = csub(E3, c3);
}

// full 8-point DFT (DIT even/odd split)
__device__ __forceinline__ void dft8(const float2* x, float2* y) {
    float2 a0=x[0], a1=x[2], a2=x[4], a3=x[6];
    float2 b0=x[1], b1=x[3], b2=x[5], b3=x[7];
    float2 ta0=cadd(a0,a2), ta1=csub(a0,a2), ta2=cadd(a1,a3), ta3=csub(a1,a3);
    float2 E0=cadd(ta0,ta2), E2=csub(ta0,ta2);
    float2 E1=cadd(ta1, mul_negi(ta3)), E3=cadd(ta1, mul_posi(ta3));
    float2 tb0=cadd(b0,b2), tb1=csub(b0,b2), tb2=cadd(b1,b3), tb3=csub(b1,b3);
    float2 O0=cadd(tb0,tb2), O2=csub(tb0,tb2);
    float2 O1=cadd(tb1, mul_negi(tb3)), O3=cadd(tb1, mul_posi(tb3));
    dft8_combine(E0,E1,E2,E3,O0,O1,O2,O3,y);
}

// 8-point DFT with x[2..5]==0 (only x0,x1,x6,x7 nonzero)
__device__ __forceinline__ void dft8_pruned(float2 x0, float2 x1, float2 x6, float2 x7, float2* y) {
    float2 E0 = cadd(x0, x6), E2 = csub(x0, x6);
    float2 E1 = cadd(x0, mul_posi(x6)), E3 = cadd(x0, mul_negi(x6));
    float2 O0 = cadd(x1, x7), O2 = csub(x1, x7);
    float2 O1 = cadd(x1, mul_posi(x7)), O3 = cadd(x1, mul_negi(x7));
    dft8_combine(E0,E1,E2,E3,O0,O1,O2,O3,y);
}

// post-butterfly twiddle for Stockham DIF stage S: y[q] *= e^{-2πi·j·q/(8l)}
template<int S>
__device__ __forceinline__ void twiddle8(int t, float2* y) {
    if (S < 2) {
        int j = (S == 0) ? t : (t >> 3);
        const float scale = (S == 0) ? (-2.0f*PI_F/512.0f) : (-2.0f*PI_F/64.0f);
        float theta = scale * (float)j;
        float sn, cs;
        __sincosf(theta, &sn, &cs);              // sin FIRST, cos second
        float2 w = make_float2(cs, sn), wq = w;
        y[1] = cmul(y[1], wq);
        #pragma unroll
        for (int q = 2; q < 8; ++q) { wq = cmul(wq, w); y[q] = cmul(y[q], wq); }
    }
}

// ---------------------------------------------------------------- pass 1
// Radix-8 row FFT. 4 rows/block, 64 threads/row. Only the 256 nonzero rows
// per batch are launched (zero band y in [128,384) is never read by pass2).
// Stage 0 feeds directly from global: shifted row x[t+64p] nonzero only at
// p=0,1,6,7. batch = blk&7 for XCD affinity.
__global__ __launch_bounds__(256) void pass1_rowfft(const float* __restrict__ image,
                                                    float2* __restrict__ T) {
    __shared__ float2 sm[2][4][578];
    int tid = threadIdx.x;
    int r = tid >> 6, t = tid & 63;
    int blk = blockIdx.x;
    int b = blk & 7;
    int g = blk >> 3;                               // 0..63
    int y0 = (g < 32) ? (g << 2) : ((g << 2) + 256);
    int y = y0 + r;
    int iy = (y < 128) ? (y + 128) : (y - 384);
    float ay = apod(iy);
    const float* irow = image + ((size_t)(b * NSZ + iy)) * NSZ;

    float2 y8[8];
    // ---- stage 0 (pruned, from global): x[p]=shifted[t+64p]
    {
        int ix0 = t + 128, ix1 = t + 192, ix6 = t, ix7 = t + 64;
        float2 x0 = make_float2(irow[ix0] * ay * apod(ix0), 0.f);
        float2 x1 = make_float2(irow[ix1] * ay * apod(ix1), 0.f);
        float2 x6 = make_float2(irow[ix6] * ay * apod(ix6), 0.f);
        float2 x7 = make_float2(irow[ix7] * ay * apod(ix7), 0.f);
        dft8_pruned(x0, x1, x6, x7, y8);
        twiddle8<0>(t, y8);
    }
    float2* A  = sm[0][r];
    float2* Bf = sm[1][r];
    #pragma unroll
    for (int q = 0; q < 8; ++q) A[PADIDX((t << 3) + q)] = y8[q];
    __syncthreads();
    // ---- stage 1: A -> Bf
    {
        float2 x[8];
        #pragma unroll
        for (int p = 0; p < 8; ++p) x[p] = A[PADIDX(t + (p << 6))];
        dft8(x, y8);
        twiddle8<1>(t, y8);
        int j = t >> 3, k = t & 7, base = k + (j << 6);
        #pragma unroll
        for (int q = 0; q < 8; ++q) Bf[PADIDX(base + (q << 3))] = y8[q];
    }
    __syncthreads();
    // ---- stage 2: Bf -> global (natural order, coalesced)
    {
        float2 x[8];
        #pragma unroll
        for (int p = 0; p < 8; ++p) x[p] = Bf[PADIDX(t + (p << 6))];
        dft8(x, y8);
        float2* Trow = T + (((size_t)(b << 9) + y) << 9);
        #pragma unroll
        for (int q = 0; q < 8; ++q) Trow[t + (q << 6)] = y8[q];
    }
}

// ---------------------------------------------------------------- pass 2
// Radix-8 column FFT. 4 adjacent columns/block for coalesced global access;
// LDS load/store phases use col-fast lane mapping. Rows 128..383 of T are
// zero -> pruned stage 0, only 4 of 8 row-octants loaded.
__global__ __launch_bounds__(256) void pass2_colfft(const float2* __restrict__ T,
                                                    float2* __restrict__ kgrid) {
    __shared__ float2 sm[2][4][578];
    int tid = threadIdx.x;
    int blk = blockIdx.x;
    int b = blk & 7;
    int colbase = (blk >> 3) << 2;                  // 0..508 step 4
    const float2* Tb = T + ((size_t)b << 18);
    float2* Kb = kgrid + ((size_t)b << 18);

    { // load phase: nonzero octants e=0,1,6,7; lanes: col fast (32B chunks)
        int c = tid & 3, rr = tid >> 2;             // rr 0..63
        #pragma unroll
        for (int ei = 0; ei < 4; ++ei) {
            int e = (ei < 2) ? ei : (ei + 4);
            int row = rr + (e << 6);
            sm[0][c][PADIDX(row)] = Tb[((size_t)row << 9) + colbase + c];
        }
    }
    __syncthreads();
    int col = tid >> 6, t = tid & 63;
    float2* A  = sm[0][col];
    float2* Bf = sm[1][col];
    float2 y8[8];
    // ---- stage 0 (pruned): A -> Bf
    {
        float2 x0 = A[PADIDX(t)];
        float2 x1 = A[PADIDX(t + 64)];
        float2 x6 = A[PADIDX(t + 384)];
        float2 x7 = A[PADIDX(t + 448)];
        dft8_pruned(x0, x1, x6, x7, y8);
        twiddle8<0>(t, y8);
    }
    #pragma unroll
    for (int q = 0; q < 8; ++q) Bf[PADIDX((t << 3) + q)] = y8[q];
    __syncthreads();
    // ---- stage 1: Bf -> A
    {
        float2 x[8];
        #pragma unroll
        for (int p = 0; p < 8; ++p) x[p] = Bf[PADIDX(t + (p << 6))];
        dft8(x, y8);
        twiddle8<1>(t, y8);
        int j = t >> 3, k = t & 7, base = k + (j << 6);
        #pragma unroll
        for (int q = 0; q < 8; ++q) A[PADIDX(base + (q << 3))] = y8[q];
    }
    __syncthreads();
    // ---- stage 2: A -> Bf (natural order)
    {
        float2 x[8];
        #pragma unroll
        for (int p = 0; p < 8; ++p) x[p] = A[PADIDX(t + (p << 6))];
        dft8(x, y8);
        #pragma unroll
        for (int q = 0; q < 8; ++q) Bf[PADIDX(t + (q << 6))] = y8[q];
    }
    __syncthreads();
    { // store phase: col-fast lanes, all 8 octants
        int c = tid & 3, rr = tid >> 2;
        #pragma unroll
        for (int e = 0; e < 8; ++e) {
            int row = rr + (e << 6);
            Kb[((size_t)row << 9) + colbase + c] = sm[1][c][PADIDX(row)];
        }
    }
}

// ---------------------------------------------------------------- pass 3
// 6x6 KB gather. batch = blk&7 -> all blocks of batch b land on XCD b
// (round-robin dispatch), so the 2 MB per-batch grid stays L2-resident.
__global__ __launch_bounds__(256) void interp_kb(const float* __restrict__ ktraj,
                                                 const float* __restrict__ dcf,
                                                 const float2* __restrict__ kgrid,
                                                 float* __restrict__ out) {
    int blk = blockIdx.x;
    int b = blk & 7;
    int m = ((blk >> 3) << 8) + threadIdx.x;    // 0..131071
    int gid = (b << 17) + m;

    const float SCALE = (float)GSZ / (2.0f * PI_F);
    float tm1 = ktraj[((size_t)b * 2) * MPTS + m] * SCALE;
    float tm2 = ktraj[((size_t)b * 2 + 1) * MPTS + m] * SCALE;
    float f1 = floorf(tm1), f2 = floorf(tm2);

    float w1[6], w2[6];
    int i1[6], i2[6];
    #pragma unroll
    for (int j = 0; j < 6; ++j) {
        float off = (float)(j - 2);
        float u1 = tm1 - (f1 + off);
        float u2 = tm2 - (f2 + off);
        float x1 = u1 * (1.0f / 3.0f);
        float x2 = u2 * (1.0f / 3.0f);
        float t1 = 1.0f - x1 * x1;
        float t2 = 1.0f - x2 * x2;
        w1[j] = (t1 > 0.f) ? bessi0(BETA_F * sqrtf(t1)) : 0.f;
        w2[j] = (t2 > 0.f) ? bessi0(BETA_F * sqrtf(t2)) : 0.f;
        i1[j] = ((int)(f1 + off)) & 511;
        i2[j] = ((int)(f2 + off)) & 511;
    }

    const float2* Kb = kgrid + ((size_t)b << 18);
    float re = 0.f, im = 0.f;
    #pragma unroll
    for (int a = 0; a < 6; ++a) {
        const float2* Krow = Kb + ((size_t)i1[a] << 9);
        float rr = 0.f, ii = 0.f;
        #pragma unroll
        for (int c = 0; c < 6; ++c) {
            float2 v = Krow[i2[c]];
            rr += v.x * w2[c];
            ii += v.y * w2[c];
        }
        re += w1[a] * rr;
        im += w1[a] * ii;
    }
    float d = dcf[gid];
    out[gid] = re * d;
    out[gid + NBATCH * MPTS] = im * d;
}

// ---------------------------------------------------------------- launch

extern "C" void kernel_launch(void* const* d_in, const int* in_sizes, int n_in,
                              void* d_out, int out_size, void* d_ws, size_t ws_size,
                              hipStream_t stream) {
    const float* image = (const float*)d_in[0];   // (8,256,256) f32
    const float* ktraj = (const float*)d_in[1];   // (8,2,131072) f32
    const float* dcf   = (const float*)d_in[2];   // (8,131072) f32
    float* out = (float*)d_out;                   // (2,8,131072) f32

    float2* T     = (float2*)d_ws;
    float2* kgrid = T + (size_t)NBATCH * GSZ * GSZ;

    pass1_rowfft<<<NBATCH * 64, 256, 0, stream>>>(image, T);     // 256 nonzero rows / 4 per block
    pass2_colfft<<<NBATCH * 128, 256, 0, stream>>>(T, kgrid);    // 512 cols / 4 per block
    interp_kb<<<(NBATCH * MPTS) / 256, 256, 0, stream>>>(ktraj, dcf, kgrid, out);
}

// Round 4
// 132.050 us; speedup vs baseline: 1.6006x; 1.2752x over previous
//
#include <hip/hip_runtime.h>
#include <math.h>

#define GSZ 512
#define NSZ 256
#define NBATCH 8
#define MPTS 131072
#define PI_F 3.14159265358979f
#define BETA_F 13.8551004f
#define BETA2_F (BETA_F * BETA_F)
#define RSQ2 0.70710678f
// LDS pad: +1 float2 every 8 → stage-0/1 strided writes drop 32-way→4-way
#define PADIDX(i) ((i) + ((i) >> 3))

// ---------------------------------------------------------------- helpers

__device__ __forceinline__ float apod(int i) {
    float x = (float)(i - 128);
    float arg = PI_F * 6.0f * x * (1.0f / 512.0f);
    float t = BETA2_F - arg * arg;
    float st = sqrtf(t);
    return st / sinhf(st);
}

__device__ __forceinline__ float bessi0(float x) {
    float ax = fabsf(x);
    if (ax < 3.75f) {
        float y = ax * (1.0f / 3.75f);
        y *= y;
        return 1.0f + y * (3.5156229f + y * (3.0899424f + y * (1.2067492f
             + y * (0.2659732f + y * (0.0360768f + y * 0.0045813f)))));
    } else {
        float y = 3.75f / ax;
        float p = 0.39894228f + y * (0.01328592f + y * (0.00225319f + y * (-0.00157565f
             + y * (0.00916281f + y * (-0.02057706f + y * (0.02635537f + y * (-0.01647633f
             + y * 0.00392377f)))))));
        return p * __expf(ax) * rsqrtf(ax);
    }
}

// Kaiser-Bessel kernel weight at offset u (support |u|<3, else 0)
__device__ __forceinline__ float kbweight(float u) {
    float x = u * (1.0f / 3.0f);
    float t = 1.0f - x * x;
    return (t > 0.f) ? bessi0(BETA_F * sqrtf(t)) : 0.f;
}

__device__ __forceinline__ float2 cadd(float2 a, float2 b){ return make_float2(a.x+b.x, a.y+b.y); }
__device__ __forceinline__ float2 csub(float2 a, float2 b){ return make_float2(a.x-b.x, a.y-b.y); }
__device__ __forceinline__ float2 cmul(float2 a, float2 b){ return make_float2(a.x*b.x-a.y*b.y, a.x*b.y+a.y*b.x); }
__device__ __forceinline__ float2 mul_negi(float2 a){ return make_float2(a.y, -a.x); }
__device__ __forceinline__ float2 mul_posi(float2 a){ return make_float2(-a.y, a.x); }
__device__ __forceinline__ float2 mul_w81(float2 a){ return make_float2(RSQ2*(a.x+a.y), RSQ2*(a.y-a.x)); }
__device__ __forceinline__ float2 mul_w83(float2 a){ return make_float2(RSQ2*(a.y-a.x), -RSQ2*(a.x+a.y)); }

__device__ __forceinline__ void dft8_combine(float2 E0, float2 E1, float2 E2, float2 E3,
                                             float2 O0, float2 O1, float2 O2, float2 O3,
                                             float2* y) {
    float2 c1 = mul_w81(O1), c2 = mul_negi(O2), c3 = mul_w83(O3);
    y[0] = cadd(E0, O0); y[4] = csub(E0, O0);
    y[1] = cadd(E1, c1); y[5] = csub(E1, c1);
    y[2] = cadd(E2, c2); y[6] = csub(E2, c2);
    y[3] = cadd(E3, c3); y[7] = csub(E3, c3);
}

__device__ __forceinline__ void dft8(const float2* x, float2* y) {
    float2 a0=x[0], a1=x[2], a2=x[4], a3=x[6];
    float2 b0=x[1], b1=x[3], b2=x[5], b3=x[7];
    float2 ta0=cadd(a0,a2), ta1=csub(a0,a2), ta2=cadd(a1,a3), ta3=csub(a1,a3);
    float2 E0=cadd(ta0,ta2), E2=csub(ta0,ta2);
    float2 E1=cadd(ta1, mul_negi(ta3)), E3=cadd(ta1, mul_posi(ta3));
    float2 tb0=cadd(b0,b2), tb1=csub(b0,b2), tb2=cadd(b1,b3), tb3=csub(b1,b3);
    float2 O0=cadd(tb0,tb2), O2=csub(tb0,tb2);
    float2 O1=cadd(tb1, mul_negi(tb3)), O3=cadd(tb1, mul_posi(tb3));
    dft8_combine(E0,E1,E2,E3,O0,O1,O2,O3,y);
}

__device__ __forceinline__ void dft8_pruned(float2 x0, float2 x1, float2 x6, float2 x7, float2* y) {
    float2 E0 = cadd(x0, x6), E2 = csub(x0, x6);
    float2 E1 = cadd(x0, mul_posi(x6)), E3 = cadd(x0, mul_negi(x6));
    float2 O0 = cadd(x1, x7), O2 = csub(x1, x7);
    float2 O1 = cadd(x1, mul_posi(x7)), O3 = cadd(x1, mul_negi(x7));
    dft8_combine(E0,E1,E2,E3,O0,O1,O2,O3,y);
}

template<int S>
__device__ __forceinline__ void twiddle8(int t, float2* y) {
    if (S < 2) {
        int j = (S == 0) ? t : (t >> 3);
        const float scale = (S == 0) ? (-2.0f*PI_F/512.0f) : (-2.0f*PI_F/64.0f);
        float theta = scale * (float)j;
        float sn, cs;
        __sincosf(theta, &sn, &cs);              // sin FIRST, cos second
        float2 w = make_float2(cs, sn), wq = w;
        y[1] = cmul(y[1], wq);
        #pragma unroll
        for (int q = 2; q < 8; ++q) { wq = cmul(wq, w); y[q] = cmul(y[q], wq); }
    }
}

// ---------------------------------------------------------------- pass 1
__global__ __launch_bounds__(256) void pass1_rowfft(const float* __restrict__ image,
                                                    float2* __restrict__ T) {
    __shared__ float2 sm[2][4][578];
    int tid = threadIdx.x;
    int r = tid >> 6, t = tid & 63;
    int blk = blockIdx.x;
    int b = blk & 7;
    int g = blk >> 3;                               // 0..63
    int y0 = (g < 32) ? (g << 2) : ((g << 2) + 256);
    int y = y0 + r;
    int iy = (y < 128) ? (y + 128) : (y - 384);
    float ay = apod(iy);
    const float* irow = image + ((size_t)(b * NSZ + iy)) * NSZ;

    float2 y8[8];
    {
        int ix0 = t + 128, ix1 = t + 192, ix6 = t, ix7 = t + 64;
        float2 x0 = make_float2(irow[ix0] * ay * apod(ix0), 0.f);
        float2 x1 = make_float2(irow[ix1] * ay * apod(ix1), 0.f);
        float2 x6 = make_float2(irow[ix6] * ay * apod(ix6), 0.f);
        float2 x7 = make_float2(irow[ix7] * ay * apod(ix7), 0.f);
        dft8_pruned(x0, x1, x6, x7, y8);
        twiddle8<0>(t, y8);
    }
    float2* A  = sm[0][r];
    float2* Bf = sm[1][r];
    #pragma unroll
    for (int q = 0; q < 8; ++q) A[PADIDX((t << 3) + q)] = y8[q];
    __syncthreads();
    {
        float2 x[8];
        #pragma unroll
        for (int p = 0; p < 8; ++p) x[p] = A[PADIDX(t + (p << 6))];
        dft8(x, y8);
        twiddle8<1>(t, y8);
        int j = t >> 3, k = t & 7, base = k + (j << 6);
        #pragma unroll
        for (int q = 0; q < 8; ++q) Bf[PADIDX(base + (q << 3))] = y8[q];
    }
    __syncthreads();
    {
        float2 x[8];
        #pragma unroll
        for (int p = 0; p < 8; ++p) x[p] = Bf[PADIDX(t + (p << 6))];
        dft8(x, y8);
        float2* Trow = T + (((size_t)(b << 9) + y) << 9);
        #pragma unroll
        for (int q = 0; q < 8; ++q) Trow[t + (q << 6)] = y8[q];
    }
}

// ---------------------------------------------------------------- pass 2
__global__ __launch_bounds__(256) void pass2_colfft(const float2* __restrict__ T,
                                                    float2* __restrict__ kgrid) {
    __shared__ float2 sm[2][4][578];
    int tid = threadIdx.x;
    int blk = blockIdx.x;
    int b = blk & 7;
    int colbase = (blk >> 3) << 2;
    const float2* Tb = T + ((size_t)b << 18);
    float2* Kb = kgrid + ((size_t)b << 18);

    {
        int c = tid & 3, rr = tid >> 2;
        #pragma unroll
        for (int ei = 0; ei < 4; ++ei) {
            int e = (ei < 2) ? ei : (ei + 4);
            int row = rr + (e << 6);
            sm[0][c][PADIDX(row)] = Tb[((size_t)row << 9) + colbase + c];
        }
    }
    __syncthreads();
    int col = tid >> 6, t = tid & 63;
    float2* A  = sm[0][col];
    float2* Bf = sm[1][col];
    float2 y8[8];
    {
        float2 x0 = A[PADIDX(t)];
        float2 x1 = A[PADIDX(t + 64)];
        float2 x6 = A[PADIDX(t + 384)];
        float2 x7 = A[PADIDX(t + 448)];
        dft8_pruned(x0, x1, x6, x7, y8);
        twiddle8<0>(t, y8);
    }
    #pragma unroll
    for (int q = 0; q < 8; ++q) Bf[PADIDX((t << 3) + q)] = y8[q];
    __syncthreads();
    {
        float2 x[8];
        #pragma unroll
        for (int p = 0; p < 8; ++p) x[p] = Bf[PADIDX(t + (p << 6))];
        dft8(x, y8);
        twiddle8<1>(t, y8);
        int j = t >> 3, k = t & 7, base = k + (j << 6);
        #pragma unroll
        for (int q = 0; q < 8; ++q) A[PADIDX(base + (q << 3))] = y8[q];
    }
    __syncthreads();
    {
        float2 x[8];
        #pragma unroll
        for (int p = 0; p < 8; ++p) x[p] = A[PADIDX(t + (p << 6))];
        dft8(x, y8);
        #pragma unroll
        for (int q = 0; q < 8; ++q) Bf[PADIDX(t + (q << 6))] = y8[q];
    }
    __syncthreads();
    {
        int c = tid & 3, rr = tid >> 2;
        #pragma unroll
        for (int e = 0; e < 8; ++e) {
            int row = rr + (e << 6);
            Kb[((size_t)row << 9) + colbase + c] = sm[1][c][PADIDX(row)];
        }
    }
}

// ---------------------------------------------------------------- pass 3
// Wave-cooperative KB gather: 8 lanes per point. Lane j owns column tap j
// (taps j>=6 fall outside |u|<3 and get weight 0 automatically). Per row
// iteration a group loads 8 contiguous float2 (64B, <=2 cache lines), so a
// wave-instruction touches ~16 distinct lines instead of 64 (TA divergence
// was the round-3 bottleneck). w1[a] broadcast by shuffle from lane a;
// xor-butterfly leaves the group sum in all lanes; lane 0 stores re, lane 1
// stores im (stores coalesce across the 8 groups of the wave).
__global__ __launch_bounds__(256) void interp_kb(const float* __restrict__ ktraj,
                                                 const float* __restrict__ dcf,
                                                 const float2* __restrict__ kgrid,
                                                 float* __restrict__ out) {
    int tid = threadIdx.x;
    int blk = blockIdx.x;
    int b = blk & 7;                         // XCD affinity
    int g = tid >> 3;                        // group in block: 0..31
    int j = tid & 7;                         // lane within group
    int m = ((blk >> 3) << 5) + g;           // point index 0..131071
    int gid = (b << 17) + m;

    const float SCALE = (float)GSZ / (2.0f * PI_F);
    float tm1 = ktraj[((size_t)b * 2) * MPTS + m] * SCALE;
    float tm2 = ktraj[((size_t)b * 2 + 1) * MPTS + m] * SCALE;
    float f1 = floorf(tm1), f2 = floorf(tm2);
    int if1 = (int)f1, if2 = (int)f2;

    // own-column weight and index (j in 0..7; j>=6 -> weight 0)
    float w2_own = kbweight(tm2 - f2 - (float)(j - 2));
    int   i2_own = (if2 + j - 2) & 511;
    // own-row weight (lane a of the group supplies w1[a] via shuffle)
    float w1_own = kbweight(tm1 - f1 - (float)(j - 2));

    int lane = tid & 63;
    int gbase = lane & 56;                   // first lane of this 8-lane group

    const float2* Kb = kgrid + ((size_t)b << 18);
    float s_re = 0.f, s_im = 0.f;
    #pragma unroll
    for (int a = 0; a < 6; ++a) {
        int i1a = (if1 + a - 2) & 511;
        float w1a = __shfl(w1_own, gbase + a, 64);
        float2 v = Kb[((size_t)i1a << 9) + i2_own];
        s_re = fmaf(w1a, v.x, s_re);
        s_im = fmaf(w1a, v.y, s_im);
    }
    float p_re = w2_own * s_re;
    float p_im = w2_own * s_im;
    // butterfly sum over the 8-lane group; all lanes end with the total
    #pragma unroll
    for (int d = 1; d < 8; d <<= 1) {
        p_re += __shfl_xor(p_re, d, 64);
        p_im += __shfl_xor(p_im, d, 64);
    }
    float dd = dcf[gid];
    if (j == 0) out[gid] = p_re * dd;                  // real plane
    if (j == 1) out[gid + NBATCH * MPTS] = p_im * dd;  // imag plane
}

// ---------------------------------------------------------------- launch

extern "C" void kernel_launch(void* const* d_in, const int* in_sizes, int n_in,
                              void* d_out, int out_size, void* d_ws, size_t ws_size,
                              hipStream_t stream) {
    const float* image = (const float*)d_in[0];   // (8,256,256) f32
    const float* ktraj = (const float*)d_in[1];   // (8,2,131072) f32
    const float* dcf   = (const float*)d_in[2];   // (8,131072) f32
    float* out = (float*)d_out;                   // (2,8,131072) f32

    float2* T     = (float2*)d_ws;
    float2* kgrid = T + (size_t)NBATCH * GSZ * GSZ;

    pass1_rowfft<<<NBATCH * 64, 256, 0, stream>>>(image, T);
    pass2_colfft<<<NBATCH * 128, 256, 0, stream>>>(T, kgrid);
    // 32 points per block (8 lanes/point)
    interp_kb<<<NBATCH * (MPTS / 32), 256, 0, stream>>>(ktraj, dcf, kgrid, out);
}